// Round 11
// baseline (221.700 us; speedup 1.0000x reference)
//
#include <hip/hip_runtime.h>
#include <hip/hip_bf16.h>
#include <math.h>

#define E 1024
#define H 16
#define HD 64
#define B 32
#define S 2048
#define CH 16           // 128-token chunks per batch row
#define CTOK (S / CH)   // 128 tokens per chunk
#define SUB 32          // tokens per sub-tile
#define NSUB (CTOK / SUB)
#define BHE (B * H * E)
#define PSTR 17         // pcur padded stride (bank-spread for strided reads)

typedef __attribute__((ext_vector_type(8))) short short8;
typedef __attribute__((ext_vector_type(4))) float f32x4;

__device__ __forceinline__ short f2bf(float f) {
    union { __hip_bfloat16 h; short s; } u;
    u.h = __float2bfloat16(f);
    return u.s;
}

// ---------------------------------------------------------------- qu: q = Wq@seed+bq then ubf[h] = bf16(scale * q_h^T Wk_h)
// one block per head h
__global__ __launch_bounds__(256) void qu_kernel(const float* __restrict__ W,
                                                 const float* __restrict__ bqkv,
                                                 const float* __restrict__ seed,
                                                 short* __restrict__ ubf) {
    int h = blockIdx.x, tid = threadIdx.x, lane = tid & 63, wv = tid >> 6;
    __shared__ float qs[HD];
    const float4* sd = (const float4*)seed;
    // phase A: q slice rows h*64 + r (wave per row, 16 rows per wave)
    for (int rr = 0; rr < 16; ++rr) {
        int r = wv * 16 + rr;
        const float4* row = (const float4*)(W + (size_t)(h * HD + r) * E);
        float acc = 0.f;
#pragma unroll
        for (int k = 0; k < 4; ++k) {
            float4 w4 = row[k * 64 + lane];
            float4 s4 = sd[k * 64 + lane];
            acc = fmaf(w4.x, s4.x, acc); acc = fmaf(w4.y, s4.y, acc);
            acc = fmaf(w4.z, s4.z, acc); acc = fmaf(w4.w, s4.w, acc);
        }
#pragma unroll
        for (int off = 32; off > 0; off >>= 1) acc += __shfl_down(acc, off, 64);
        if (lane == 0) qs[r] = acc + bqkv[h * HD + r];
    }
    __syncthreads();
    // phase B: u row h, coalesced column reads of Wk
#pragma unroll
    for (int j = 0; j < 4; ++j) {
        int e = tid + j * 256;
        const float* Wk = W + ((size_t)(E + h * HD)) * E + e;
        float acc = 0.f;
#pragma unroll 8
        for (int d = 0; d < HD; ++d) acc = fmaf(qs[d], Wk[(size_t)d * E], acc);
        ubf[(size_t)h * E + e] = f2bf(acc * 0.125f);  // 1/sqrt(64)
    }
}

// ---------------------------------------------------------------- fused single-pass flash kernel per (chunk, b)
// 4 sub-tiles of 32 tokens:
//   stage:  x -> bf16 -> swizzled LDS (byte ^= (tok&7)<<4); masked tokens write ZEROS
//   scores: 8 waves = 2 token-tiles x 4 K-quarters, mfma_f32_16x16x32_bf16 (verified mapping)
//   online softmax -> p (f32, [tok][h] stride 17), running m/l, rfac
//   pool:   MFMA! D[h][e-tile] += P^T(A, bf16 from pcur) x X(B, u16 col reads from xB);
//           accumulator rescaled by rfac[head] each sub-tile. No branches, no VALU storm.
__global__ __launch_bounds__(512, 4) void fused_kernel(const float* __restrict__ x,
                                                       const int* __restrict__ mask,
                                                       const short* __restrict__ ubf,
                                                       float* __restrict__ part,
                                                       float* __restrict__ mstat,
                                                       float* __restrict__ lstat) {
    int ss = blockIdx.x, b = blockIdx.y;
    __shared__ short xB[SUB * E];          // 64 KB bf16 [tok][e], XOR-swizzled
    __shared__ float scp[8 * 64 * 4];      // 8 KB cross-kq partials
    __shared__ float pcur[SUB * PSTR];     // p [tok][h], stride 17
    __shared__ int   mk[CTOK];
    __shared__ float mrun[H], lrun[H], rfac[H];
    __shared__ float wred[8][16];

    int tid = threadIdx.x, lane = tid & 63, wid = tid >> 6;
    int col = lane & 15, kg4 = lane >> 4;

    if (tid < H) { mrun[tid] = -1e30f; lrun[tid] = 0.f; }
    for (int i = tid; i < CTOK; i += 512) mk[i] = mask[(size_t)b * S + ss * CTOK + i];

    f32x4 pacc[8];
#pragma unroll
    for (int et = 0; et < 8; ++et) pacc[et] = (f32x4){0.f, 0.f, 0.f, 0.f};

    __syncthreads();

    for (int sub = 0; sub < NSUB; ++sub) {
        int t0 = sub * SUB;

        // ---- stage x -> xB (masked tokens -> zeros) ----
        {
            int tok = tid >> 4;
            int es  = tid & 15;
            const float* xr = x + ((size_t)b * S + ss * CTOK + t0 + tok) * E;
            bool live = mk[t0 + tok] != 0;
            int sw = (tok & 7) << 4;
#pragma unroll
            for (int i = 0; i < 8; ++i) {
                int e0 = (es + i * 16) * 8;
                short8 v = (short8){0, 0, 0, 0, 0, 0, 0, 0};
                if (live) {
                    float4 lo = *(const float4*)(xr + e0);
                    float4 hi = *(const float4*)(xr + e0 + 4);
                    v[0] = f2bf(lo.x); v[1] = f2bf(lo.y); v[2] = f2bf(lo.z); v[3] = f2bf(lo.w);
                    v[4] = f2bf(hi.x); v[5] = f2bf(hi.y); v[6] = f2bf(hi.z); v[7] = f2bf(hi.w);
                }
                int byte = (tok * 2048 + e0 * 2) ^ sw;
                *(short8*)((char*)xB + byte) = v;
            }
        }
        __syncthreads();

        // ---- MFMA scores: wave (tw = wid&1, kq = wid>>1) ----
        {
            int tw = wid & 1, kq = wid >> 1;
            int tok = tw * 16 + col;
            int sw = (tok & 7) << 4;
            f32x4 acc = (f32x4){0.f, 0.f, 0.f, 0.f};
            const short* ub = ubf + (size_t)col * E;
#pragma unroll
            for (int st = 0; st < 8; ++st) {
                int e0 = kq * 256 + st * 32 + kg4 * 8;
                int byte = (tok * 2048 + e0 * 2) ^ sw;
                short8 a = *(const short8*)((char*)xB + byte);
                short8 bv = *(const short8*)(ub + e0);
                acc = __builtin_amdgcn_mfma_f32_16x16x32_bf16(a, bv, acc, 0, 0, 0);
            }
            *(f32x4*)&scp[(wid * 64 + lane) * 4] = acc;
        }
        __syncthreads();

        // ---- reduce over kq + online softmax update ----
        {
            int tok = tid >> 4, h = tid & 15;
            int tw = tok >> 4, r = tok & 3, kg2 = (tok & 15) >> 2;
            float s = 0.f;
#pragma unroll
            for (int kq = 0; kq < 4; ++kq)
                s += scp[((kq * 2 + tw) * 64 + kg2 * 16 + h) * 4 + r];
            bool live = mk[t0 + tok] != 0;
            float sv = live ? s : -1e30f;
            float mx = sv;
            mx = fmaxf(mx, __shfl_xor(mx, 16, 64));
            mx = fmaxf(mx, __shfl_xor(mx, 32, 64));
            if (lane < 16) wred[wid][lane] = mx;
            __syncthreads();
            if (tid < 16) {
                float mt = wred[0][tid];
#pragma unroll
                for (int w = 1; w < 8; ++w) mt = fmaxf(mt, wred[w][tid]);
                float mo = mrun[tid];
                float mn = fmaxf(mo, mt);
                rfac[tid] = __expf(mo - mn);
                mrun[tid] = mn;
            }
            __syncthreads();
            float p = live ? __expf(s - mrun[h]) : 0.f;
            pcur[tok * PSTR + h] = p;
            float ps = p;
            ps += __shfl_xor(ps, 16, 64);
            ps += __shfl_xor(ps, 32, 64);
            if (lane < 16) wred[wid][lane] = ps;
            __syncthreads();
            if (tid < 16) {
                float lt = 0.f;
#pragma unroll
                for (int w = 0; w < 8; ++w) lt += wred[w][tid];
                lrun[tid] = lrun[tid] * rfac[tid] + lt;
            }
        }
        __syncthreads();

        // ---- pool via MFMA: D[h][e] += P^T . X ----
        {
            float rf0 = rfac[kg4 * 4 + 0];
            float rf1 = rfac[kg4 * 4 + 1];
            float rf2 = rfac[kg4 * 4 + 2];
            float rf3 = rfac[kg4 * 4 + 3];
#pragma unroll
            for (int et = 0; et < 8; ++et) {
                pacc[et][0] *= rf0; pacc[et][1] *= rf1;
                pacc[et][2] *= rf2; pacc[et][3] *= rf3;
            }
            // A-frag: head = col, tokens kg4*8 + j
            short8 af;
#pragma unroll
            for (int j = 0; j < 8; ++j)
                af[j] = f2bf(pcur[(kg4 * 8 + j) * PSTR + col]);
            // B-frags: e-col = wid*128 + et*16 + col, tokens kg4*8 + j
            int ebase = wid * 128;
#pragma unroll
            for (int et = 0; et < 8; ++et) {
                short8 bf;
#pragma unroll
                for (int j = 0; j < 8; ++j) {
                    int tok = kg4 * 8 + j;   // tok&7 == j
                    int byte = (tok * 2048 + (ebase + et * 16 + col) * 2) ^ (j << 4);
                    bf[j] = *(const short*)((const char*)xB + byte);
                }
                pacc[et] = __builtin_amdgcn_mfma_f32_16x16x32_bf16(af, bf, pacc[et], 0, 0, 0);
            }
        }
        __syncthreads();  // protect xB/pcur before next stage
    }

    // ---- write unnormalized partial + stats ----
    float* pb = part + ((size_t)ss * B + b) * (H * E);
#pragma unroll
    for (int et = 0; et < 8; ++et) {
#pragma unroll
        for (int r = 0; r < 4; ++r)
            pb[(size_t)(kg4 * 4 + r) * E + wid * 128 + et * 16 + col] = pacc[et][r];
    }
    if (tid < 16) {
        mstat[((size_t)ss * B + b) * H + tid] = mrun[tid];
        lstat[((size_t)ss * B + b) * H + tid] = lrun[tid];
    }
}

// ---------------------------------------------------------------- ctxc: combine chunk partials (online-softmax rescale) + Wv projection
__global__ __launch_bounds__(256) void ctxc_kernel(const float* __restrict__ W,
                                                   const float* __restrict__ bqkv,
                                                   const float* __restrict__ part,
                                                   const float* __restrict__ mstat,
                                                   const float* __restrict__ lstat,
                                                   float* __restrict__ ctx) {
    int cb = blockIdx.x, b = blockIdx.y, t = threadIdx.x;
    int h0 = cb * 4;
    __shared__ float xls[4 * E];  // 16 KB
    __shared__ float fs[4][CH];
    __shared__ float linv[4];
    if (t < 4) {
        int h = h0 + t;
        float mv[CH];
        float mg = -1e30f;
#pragma unroll
        for (int c = 0; c < CH; ++c) {
            mv[c] = mstat[((size_t)c * B + b) * H + h];
            mg = fmaxf(mg, mv[c]);
        }
        float l = 0.f;
#pragma unroll
        for (int c = 0; c < CH; ++c) {
            float fc = __expf(mv[c] - mg);
            fs[t][c] = fc;
            l = fmaf(fc, lstat[((size_t)c * B + b) * H + h], l);
        }
        linv[t] = 1.f / l;
    }
    __syncthreads();
    for (int i = t; i < 4 * E / 4; i += 256) {
        int hl = i >> 8, e4 = i & 255;
        float4 s = make_float4(0.f, 0.f, 0.f, 0.f);
#pragma unroll 4
        for (int c = 0; c < CH; ++c) {
            float fc = fs[hl][c];
            float4 v = ((const float4*)part)[(((size_t)c * B + b) * H + h0 + hl) * (E / 4) + e4];
            s.x = fmaf(fc, v.x, s.x); s.y = fmaf(fc, v.y, s.y);
            s.z = fmaf(fc, v.z, s.z); s.w = fmaf(fc, v.w, s.w);
        }
        float li = linv[hl];
        s.x *= li; s.y *= li; s.z *= li; s.w *= li;
        ((float4*)xls)[i] = s;
    }
    __syncthreads();
    int c = cb * 256 + t;
    int h = c >> 6;
    const float4* wr = (const float4*)(W + ((size_t)(2 * E + c)) * E);
    const float4* xl = (const float4*)(xls + (h - h0) * E);
    float acc = bqkv[2 * E + c];
#pragma unroll 4
    for (int e4 = 0; e4 < E / 4; ++e4) {
        float4 w = wr[e4], xv = xl[e4];
        acc = fmaf(w.x, xv.x, acc); acc = fmaf(w.y, xv.y, acc);
        acc = fmaf(w.z, xv.z, acc); acc = fmaf(w.w, xv.w, acc);
    }
    ctx[(size_t)b * E + c] = acc;
}

// ---------------------------------------------------------------- outln: out = LN(Wo.ctx[b] + ob) — one block per b
__global__ __launch_bounds__(512) void outln_kernel(const float* __restrict__ Wo,
                                                    const float* __restrict__ ob,
                                                    const float* __restrict__ ctx,
                                                    const float* __restrict__ g,
                                                    const float* __restrict__ lb,
                                                    float* __restrict__ out) {
    int b = blockIdx.x, t = threadIdx.x, lane = t & 63, wv = t >> 6;
    __shared__ float cl[E];
    __shared__ float rs[8], rq[8];
    const float4* cp = (const float4*)(ctx + (size_t)b * E);
    for (int i = t; i < E / 4; i += 512) ((float4*)cl)[i] = cp[i];
    __syncthreads();
    float acc[2];
#pragma unroll
    for (int j = 0; j < 2; ++j) {
        int o = t + j * 512;
        const float4* wr = (const float4*)(Wo + (size_t)o * E);
        const float4* cl4 = (const float4*)cl;
        float a = ob[o];
#pragma unroll 4
        for (int e4 = 0; e4 < E / 4; ++e4) {
            float4 w = wr[e4], cv = cl4[e4];
            a = fmaf(w.x, cv.x, a); a = fmaf(w.y, cv.y, a);
            a = fmaf(w.z, cv.z, a); a = fmaf(w.w, cv.w, a);
        }
        acc[j] = a;
    }
    float s = acc[0] + acc[1];
    float sq = acc[0] * acc[0] + acc[1] * acc[1];
#pragma unroll
    for (int off = 32; off > 0; off >>= 1) {
        s += __shfl_down(s, off, 64);
        sq += __shfl_down(sq, off, 64);
    }
    if (lane == 0) { rs[wv] = s; rq[wv] = sq; }
    __syncthreads();
    s = 0.f; sq = 0.f;
#pragma unroll
    for (int w = 0; w < 8; ++w) { s += rs[w]; sq += rq[w]; }
    float mean = s * (1.f / E);
    float var = sq * (1.f / E) - mean * mean;
    float inv = rsqrtf(var + 1e-5f);
#pragma unroll
    for (int j = 0; j < 2; ++j) {
        int o = t + j * 512;
        out[(size_t)b * E + o] = (acc[j] - mean) * inv * g[o] + lb[o];
    }
}

extern "C" void kernel_launch(void* const* d_in, const int* in_sizes, int n_in,
                              void* d_out, int out_size, void* d_ws, size_t ws_size,
                              hipStream_t stream) {
    const float* x    = (const float*)d_in[0];
    const int*   mask = (const int*)d_in[1];
    const float* seed = (const float*)d_in[2];
    const float* W    = (const float*)d_in[3];  // (3E, E)
    const float* bqkv = (const float*)d_in[4];  // (3E,)
    const float* Wo   = (const float*)d_in[5];  // (E, E)
    const float* ob   = (const float*)d_in[6];  // (E,)
    const float* g    = (const float*)d_in[7];
    const float* lb   = (const float*)d_in[8];
    float* out = (float*)d_out;

    float* ws = (float*)d_ws;
    float* part   = ws;                           // CH*B*H*E
    float* mstat  = part + (size_t)CH * BHE;      // CH*B*H
    float* lstat  = mstat + (size_t)CH * B * H;   // CH*B*H
    short* ubf    = (short*)(lstat + (size_t)CH * B * H);  // H*E bf16
    float* ctx    = (float*)(ubf + (size_t)H * E);         // B*E

    qu_kernel<<<H, 256, 0, stream>>>(W, bqkv, seed, ubf);
    fused_kernel<<<dim3(CH, B), 512, 0, stream>>>(x, mask, ubf, part, mstat, lstat);
    ctxc_kernel<<<dim3(E / 256, B), 256, 0, stream>>>(W, bqkv, part, mstat, lstat, ctx);
    outln_kernel<<<B, 512, 0, stream>>>(Wo, ob, ctx, g, lb, out);
}